// Round 21
// baseline (84.354 us; speedup 1.0000x reference)
//
#include <hip/hip_runtime.h>

typedef __attribute__((ext_vector_type(8))) short short8;
typedef __attribute__((ext_vector_type(4))) float f32x4;
typedef __attribute__((ext_vector_type(4))) unsigned int u32x4;
typedef unsigned short ushort_t;

constexpr int B   = 4;
constexpr int C   = 256;
constexpr int H   = 64;
constexpr int W   = 64;
constexpr int HW  = H * W;          // 4096
constexpr int OCH = 256;
constexpr int KT  = 9 * C;          // 2304, k order: k = tap*256 + c
constexpr int NHS = KT / 32;        // 72 half-steps (MFMA K=32)

__device__ __forceinline__ ushort_t f2bf(float f) {
    unsigned u = __float_as_uint(f);
    u += 0x7FFF + ((u >> 16) & 1);      // RNE
    return (ushort_t)(u >> 16);
}

// Barrier that does NOT drain vmcnt: LDS writes are made visible
// (lgkmcnt(0)), but in-register global loads stay in flight across it.
__device__ __forceinline__ void block_sync_lds() {
    asm volatile("s_waitcnt lgkmcnt(0)" ::: "memory");
    __builtin_amdgcn_s_barrier();
    asm volatile("" ::: "memory");
}

// ---------------------------------------------------------------------------
// K0: prep = transpose (blocks 0..1023) + weight packing (blocks 1024..1347).
// Transpose: xt[b][y][x][c] (bf16) <- x[b][c][y][x] (f32); b<2 -> xt01 (ws),
// b>=2 -> xtD (d_out batch-0 scratch).  Pack: validated rounds 2-20.
// ---------------------------------------------------------------------------
__global__ __launch_bounds__(256) void prep_all(
    const float* __restrict__ x, const float* __restrict__ w_def,
    const float* __restrict__ w_off, ushort_t* __restrict__ xt01,
    ushort_t* __restrict__ xtD, ushort_t* __restrict__ wPack,
    ushort_t* __restrict__ wOffA)
{
    __shared__ float sT[64][65];
    int blk = blockIdx.x;
    if (blk < 1024) {
        int cg  = blk & 3;               // channel group of 64
        int y   = (blk >> 2) & 63;
        int b   = blk >> 8;              // 0..3
        int t   = threadIdx.x;
        int col = t & 63, r4 = t >> 6;

        const float* xp = x + (((size_t)b * C + cg * 64) * H + y) * W;
        #pragma unroll
        for (int i = 0; i < 16; ++i) {
            int cl = i * 4 + r4;
            sT[cl][col] = xp[(size_t)cl * HW + col];
        }
        __syncthreads();
        ushort_t* base = (b < 2) ? (xt01 + (size_t)b * HW * C)
                                 : (xtD + (size_t)(b - 2) * HW * C);
        ushort_t* op = base + ((size_t)y * W) * C + cg * 64;
        #pragma unroll
        for (int i = 0; i < 16; ++i) {
            int xl = i * 4 + r4;
            op[(size_t)xl * C + col] = f2bf(sT[col][xl]);
        }
    } else {
        int tid = (blk - 1024) * 256 + threadIdx.x;   // [0, 82944)
        if (tid < NHS * 16 * 64) {
            int lane = tid & 63;
            int o = ((tid >> 6) & 15) * 16 + (lane & 15);
            int kbase = (tid >> 10) * 32 + (lane >> 4) * 8;
            union { ushort_t u[8]; short8 v; } pk;
            #pragma unroll
            for (int j = 0; j < 8; ++j) {
                int kidx = kbase + j;
                int c = kidx & 255, tap = kidx >> 8;
                pk.u[j] = f2bf(w_def[((size_t)o * C + c) * 9 + tap]);
            }
            *(short8*)(wPack + (size_t)tid * 8) = pk.v;
        } else {
            int t2 = tid - NHS * 16 * 64;             // [0, 9216)
            int lane = t2 & 63;
            int o = ((t2 >> 6) & 1) * 16 + (lane & 15);
            int kbase = (t2 >> 7) * 32 + (lane >> 4) * 8;
            union { ushort_t u[8]; short8 v; } pk;
            #pragma unroll
            for (int j = 0; j < 8; ++j) {
                int kidx = kbase + j;
                int c = kidx & 255, tap = kidx >> 8;
                pk.u[j] = (o < 18) ? f2bf(w_off[((size_t)o * C + c) * 9 + tap]) : (ushort_t)0;
            }
            *(short8*)(wOffA + (size_t)t2 * 8) = pk.v;
        }
    }
}

// ---------------------------------------------------------------------------
// K4: FUSED {offset-conv MFMA prologue + bilinear sample + bf16 MFMA GEMM}.
// r20 structure with ONE change: o is split across blocks (ohalf) -> grid
// 512 blocks/launch of 128o x 32px = 2 blocks/CU, so a co-resident block
// overlaps each barrier phase.  Wave wv owns gt0 = ohalf*8 + wv (one 16-o
// tile); A[4] per sub, acc2 = 2 x f32x4.  Gathers/prologue duplicated per
// o-half (+~150 MB L2/launch) in exchange for barrier overlap.  Same K
// order per output -> bit-identical results.
// Grid (bl,ho,ohalf,pxh) = 512 blocks/launch, 512 thr, launch_bounds(512,2).
// ---------------------------------------------------------------------------
__global__ __launch_bounds__(512, 2) void deform_pair(
    const ushort_t* __restrict__ xtB, const ushort_t* __restrict__ wOffA,
    const ushort_t* __restrict__ wPack, float* __restrict__ out, int pbase)
{
    __shared__ __align__(16) ushort_t sS[2][32][33][8];  // 33.8 KB (32 slots)
    __shared__ float sOff[18][32];                       // 2.3 KB
    __shared__ float sPart[8][18][32];                   // 18.4 KB (prologue)
    __shared__ int   sBase[2][128];                      // run bases (dbuf)
    __shared__ float sWgt[2][32][4];                     // per-px nbr weights

    int orig = blockIdx.x;
    int r = ((orig & 7) << 6) | (orig >> 3);   // XCD swizzle, 512 blocks
    int bl = r >> 8, ho = (r >> 2) & 63, ohalf = (r >> 1) & 1, pxh = r & 1;
    int tid = threadIdx.x;
    int lane = tid & 63, wv = tid >> 6;        // 8 waves
    int chunk = tid & 15, rq = (tid >> 4) & 31;  // staging: pixel rq, chunk

    const ushort_t* xtb = xtB + (size_t)bl * HW * C;
    int b = pbase + bl;

    // ---------------- offset-conv prologue (split-K MFMA) ----------------
    {
        const short8* wA = (const short8*)wOffA;
        f32x4 pacc[2][2];
        #pragma unroll
        for (int i = 0; i < 2; ++i)
            #pragma unroll
            for (int j = 0; j < 2; ++j) pacc[i][j] = (f32x4){0.f, 0.f, 0.f, 0.f};

        #pragma unroll 1
        for (int i = 0; i < 9; ++i) {
            int ks = wv * 9 + i;               // this wave's K-step
            int tap = ks >> 3, cs = ks & 7;
            int ky = tap / 3, kx = tap - ky * 3;
            int y  = ho - 1 + ky;
            int yc = min(max(y, 0), 63);
            bool yok = ((unsigned)y < 64u);
            short8 a0 = wA[(size_t)ks * 128 + lane];
            short8 a1 = wA[(size_t)ks * 128 + 64 + lane];
            #pragma unroll
            for (int pt = 0; pt < 2; ++pt) {
                int px = pxh * 32 + pt * 16 + (lane & 15);
                int xx = px - 1 + kx;
                bool ok = yok && ((unsigned)xx < 64u);
                unsigned msk = ok ? 0xffffffffu : 0u;
                int xc = min(max(xx, 0), 63);
                const ushort_t* srcb = xtb + (size_t)(yc * 64 + xc) * C
                                       + cs * 32 + (lane >> 4) * 8;
                union { u32x4 u; short8 s; } bv;
                bv.u = *(const u32x4*)srcb;
                bv.u[0] &= msk; bv.u[1] &= msk; bv.u[2] &= msk; bv.u[3] &= msk;
                pacc[0][pt] = __builtin_amdgcn_mfma_f32_16x16x32_bf16(a0, bv.s, pacc[0][pt], 0, 0, 0);
                pacc[1][pt] = __builtin_amdgcn_mfma_f32_16x16x32_bf16(a1, bv.s, pacc[1][pt], 0, 0, 0);
            }
        }
        // write partials (D: row=(l>>4)*4+j, col=l&15), only oc<18
        #pragma unroll
        for (int gt = 0; gt < 2; ++gt) {
            #pragma unroll
            for (int pt = 0; pt < 2; ++pt) {
                #pragma unroll
                for (int j = 0; j < 4; ++j) {
                    int oc = gt * 16 + (lane >> 4) * 4 + j;
                    if (oc < 18)
                        sPart[wv][oc][pt * 16 + (lane & 15)] = pacc[gt][pt][j];
                }
            }
        }
    }
    __syncthreads();
    for (int idx = tid; idx < 18 * 32; idx += 512) {
        int oc = idx >> 5, q = idx & 31;
        float s = 0.f;
        #pragma unroll
        for (int g = 0; g < 8; ++g) s += sPart[g][oc][q];
        sOff[oc][q] = s;
    }
    __syncthreads();

    // ---------------- main loop ----------------
    f32x4 acc2[2];
    acc2[0] = (f32x4){0.f, 0.f, 0.f, 0.f};
    acc2[1] = (f32x4){0.f, 0.f, 0.f, 0.f};

    // run bases + per-pixel neighbor weights (validity folded in), dbuf by tap
    auto computeBase = [&](int tap, int buf) {
        if (tid < 128) {
            int n = tid >> 5, q = tid & 31;
            int ky = tap / 3, kx = tap - ky * 3;
            float offy = sOff[2 * tap][q];
            float offx = sOff[2 * tap + 1][q];
            float py  = offy + (float)(ho - 1 + ky);
            float pxf = offx + (float)(pxh * 32 + q - 1 + kx);
            float y0f = floorf(py), x0f = floorf(pxf);
            float wy1 = py - y0f, wx1 = pxf - x0f;
            int y0 = (int)y0f, x0 = (int)x0f;
            int dy = n >> 1, dx = n & 1;
            int yy = y0 + dy, xx = x0 + dx;
            float wn = (dy ? wy1 : (1.f - wy1)) * (dx ? wx1 : (1.f - wx1));
            wn *= (((unsigned)yy < 64u) ? 1.f : 0.f) * (((unsigned)xx < 64u) ? 1.f : 0.f);
            int yc = min(max(yy, 0), 63), xc = min(max(xx, 0), 63);
            sBase[buf][tid] = (yc * 64 + xc) * C;
            sWgt[buf][q][n] = wn;
        }
    };

    auto loadBases = [&](int buf, int* rb) {
        #pragma unroll
        for (int n = 0; n < 4; ++n) rb[n] = sBase[buf][n * 32 + rq];
    };

    // coalesced: 8 x 16B, neighbor n of pixel rq, both subs
    auto issueBoth = [&](const int* rb, u32x4* La, u32x4* Lb) {
        #pragma unroll
        for (int n = 0; n < 4; ++n) {
            const ushort_t* p0 = xtb + rb[n] + chunk * 8;
            La[n] = *(const u32x4*)p0;
            Lb[n] = *(const u32x4*)(p0 + 128);
        }
    };

    // in-register blend: one pixel (rq), 4 neighbors -> one sS slot
    auto blendOne = [&](const u32x4* L, const float* w, int p, int slot) {
        unsigned pk[4];
        #pragma unroll
        for (int j = 0; j < 4; ++j) {
            float f0l = __uint_as_float(L[0][j] << 16);
            float f0h = __uint_as_float(L[0][j] & 0xffff0000u);
            float f1l = __uint_as_float(L[1][j] << 16);
            float f1h = __uint_as_float(L[1][j] & 0xffff0000u);
            float f2l = __uint_as_float(L[2][j] << 16);
            float f2h = __uint_as_float(L[2][j] & 0xffff0000u);
            float f3l = __uint_as_float(L[3][j] << 16);
            float f3h = __uint_as_float(L[3][j] & 0xffff0000u);
            float lo = fmaf(w[0], f0l, fmaf(w[1], f1l, fmaf(w[2], f2l, w[3] * f3l)));
            float hi = fmaf(w[0], f0h, fmaf(w[1], f1h, fmaf(w[2], f2h, w[3] * f3h)));
            asm("v_cvt_pk_bf16_f32 %0, %1, %2" : "=v"(pk[j]) : "v"(lo), "v"(hi));
        }
        u32x4 wvec = (u32x4){pk[0], pk[1], pk[2], pk[3]};
        *(u32x4*)&sS[p][slot][rq][0] = wvec;
    };

    int gt0 = ohalf * 8 + wv;                 // this wave's single 16-o tile
    const short8* wpB = (const short8*)wPack;

    // batch-issue the 4 A-fragments of one sub (this wave's gt only)
    auto loadA4 = [&](int ks4base, short8* A) {
        #pragma unroll
        for (int h = 0; h < 4; ++h)
            A[h] = wpB[((size_t)(ks4base + h) * 16 + gt0) * 64 + lane];
    };

    auto mfmaHalf = [&](const short8* A, int p, int half) {
        __builtin_amdgcn_s_setprio(1);            // T5: favor MFMA wave
        #pragma unroll
        for (int h = 0; h < 4; ++h) {
            #pragma unroll
            for (int pt = 0; pt < 2; ++pt) {
                short8 bF = *(const short8*)&sS[p][half * 16 + h * 4 + (lane >> 4)][pt * 16 + (lane & 15)][0];
                acc2[pt] = __builtin_amdgcn_mfma_f32_16x16x32_bf16(A[h], bF, acc2[pt], 0, 0, 0);
            }
        }
        __builtin_amdgcn_s_setprio(0);
    };

    u32x4 LA[4], LB[4];
    short8 A[4];

    // prologue of main pipeline
    computeBase(0, 0);
    block_sync_lds();
    {
        int rb0[4];
        loadBases(0, rb0);
        issueBoth(rb0, LA, LB);
    }

    int p = 0;
    #pragma unroll 1
    for (int tap = 0; tap < 9; ++tap) {
        float wcur[4];
        *(float4*)&wcur[0] = *(const float4*)&sWgt[tap & 1][rq][0];
        if (tap < 8) computeBase(tap + 1, (tap + 1) & 1);

        loadA4(tap * 8, A);                 // half-0 A: hides under blend+barrier
        blendOne(LA, wcur, p, chunk);       // sub0 -> slots 0..15
        blendOne(LB, wcur, p, 16 + chunk);  // sub1 -> slots 16..31
        block_sync_lds();                   // ONE barrier per tap

        int rb[4];
        if (tap < 8) { loadBases((tap + 1) & 1, rb); issueBoth(rb, LA, LB); }

        mfmaHalf(A, p, 0);                  // sub0: 8 MFMA
        loadA4(tap * 8 + 4, A);             // half-1 A: covered by MFMA pipe
        mfmaHalf(A, p, 1);                  // sub1: 8 MFMA
        p ^= 1;
    }

    // epilogue: D[row=(l>>4)*4+j][col=l&15]
    {
        int o = gt0 * 16 + (lane >> 4) * 4;
        #pragma unroll
        for (int pt = 0; pt < 2; ++pt) {
            int pxx = pxh * 32 + pt * 16 + (lane & 15);
            #pragma unroll
            for (int j = 0; j < 4; ++j)
                out[(((size_t)b * OCH + (o + j)) * H + ho) * W + pxx] = acc2[pt][j];
        }
    }
}

// ---------------------------------------------------------------------------
extern "C" void kernel_launch(void* const* d_in, const int* in_sizes, int n_in,
                              void* d_out, int out_size, void* d_ws, size_t ws_size,
                              hipStream_t stream)
{
    const float* x     = (const float*)d_in[0];
    const float* w_off = (const float*)d_in[1];
    const float* w_def = (const float*)d_in[2];
    float* out = (float*)d_out;

    // ws: xt01[4.19MB] | wPack[1.18MB] | wOffA[147KB] = 5.52 MB (< proven 6.7).
    // xt23 lives in d_out's batch-0 region: written by prep, read by
    // deform(pbase=2) (writes out[b2,b3] only), then overwritten by
    // deform(pbase=0)'s out[b0] stores.
    ushort_t* xt01  = (ushort_t*)d_ws;
    ushort_t* wPack = xt01 + (size_t)2 * HW * C;
    ushort_t* wOffA = wPack + (size_t)NHS * 16 * 64 * 8;
    ushort_t* xtD   = (ushort_t*)d_out;   // batch 2,3 xt scratch

    prep_all<<<1348, 256, 0, stream>>>(x, w_def, w_off, xt01, xtD, wPack, wOffA);
    deform_pair<<<512, 512, 0, stream>>>(xtD, wOffA, wPack, out, 2);
    deform_pair<<<512, 512, 0, stream>>>(xt01, wOffA, wPack, out, 0);
}

// Round 22
// 64.683 us; speedup vs baseline: 1.3041x; 1.3041x over previous
//
#include <hip/hip_runtime.h>

typedef __attribute__((ext_vector_type(8))) short short8;
typedef __attribute__((ext_vector_type(4))) float f32x4;
typedef __attribute__((ext_vector_type(4))) unsigned int u32x4;
typedef unsigned short ushort_t;

constexpr int B   = 4;
constexpr int C   = 256;
constexpr int H   = 64;
constexpr int W   = 64;
constexpr int HW  = H * W;          // 4096
constexpr int OCH = 256;
constexpr int KT  = 9 * C;          // 2304, k order: k = tap*256 + c
constexpr int NHS = KT / 32;        // 72 half-steps (MFMA K=32)

__device__ __forceinline__ ushort_t f2bf(float f) {
    unsigned u = __float_as_uint(f);
    u += 0x7FFF + ((u >> 16) & 1);      // RNE
    return (ushort_t)(u >> 16);
}

// Barrier that does NOT drain vmcnt: LDS writes are made visible
// (lgkmcnt(0)), but in-register global loads stay in flight across it.
__device__ __forceinline__ void block_sync_lds() {
    asm volatile("s_waitcnt lgkmcnt(0)" ::: "memory");
    __builtin_amdgcn_s_barrier();
    asm volatile("" ::: "memory");
}

// ---------------------------------------------------------------------------
// K0: prep = transpose (blocks 0..1023) + weight packing (blocks 1024..1347).
// Transpose: xt[b][y][x][c] (bf16) <- x[b][c][y][x] (f32); b<2 -> xt01 (ws),
// b>=2 -> xtD (d_out batch-0 scratch).  Pack: validated rounds 2-20.
// ---------------------------------------------------------------------------
__global__ __launch_bounds__(256) void prep_all(
    const float* __restrict__ x, const float* __restrict__ w_def,
    const float* __restrict__ w_off, ushort_t* __restrict__ xt01,
    ushort_t* __restrict__ xtD, ushort_t* __restrict__ wPack,
    ushort_t* __restrict__ wOffA)
{
    __shared__ float sT[64][65];
    int blk = blockIdx.x;
    if (blk < 1024) {
        int cg  = blk & 3;               // channel group of 64
        int y   = (blk >> 2) & 63;
        int b   = blk >> 8;              // 0..3
        int t   = threadIdx.x;
        int col = t & 63, r4 = t >> 6;

        const float* xp = x + (((size_t)b * C + cg * 64) * H + y) * W;
        #pragma unroll
        for (int i = 0; i < 16; ++i) {
            int cl = i * 4 + r4;
            sT[cl][col] = xp[(size_t)cl * HW + col];
        }
        __syncthreads();
        ushort_t* base = (b < 2) ? (xt01 + (size_t)b * HW * C)
                                 : (xtD + (size_t)(b - 2) * HW * C);
        ushort_t* op = base + ((size_t)y * W) * C + cg * 64;
        #pragma unroll
        for (int i = 0; i < 16; ++i) {
            int xl = i * 4 + r4;
            op[(size_t)xl * C + col] = f2bf(sT[col][xl]);
        }
    } else {
        int tid = (blk - 1024) * 256 + threadIdx.x;   // [0, 82944)
        if (tid < NHS * 16 * 64) {
            int lane = tid & 63;
            int o = ((tid >> 6) & 15) * 16 + (lane & 15);
            int kbase = (tid >> 10) * 32 + (lane >> 4) * 8;
            union { ushort_t u[8]; short8 v; } pk;
            #pragma unroll
            for (int j = 0; j < 8; ++j) {
                int kidx = kbase + j;
                int c = kidx & 255, tap = kidx >> 8;
                pk.u[j] = f2bf(w_def[((size_t)o * C + c) * 9 + tap]);
            }
            *(short8*)(wPack + (size_t)tid * 8) = pk.v;
        } else {
            int t2 = tid - NHS * 16 * 64;             // [0, 9216)
            int lane = t2 & 63;
            int o = ((t2 >> 6) & 1) * 16 + (lane & 15);
            int kbase = (t2 >> 7) * 32 + (lane >> 4) * 8;
            union { ushort_t u[8]; short8 v; } pk;
            #pragma unroll
            for (int j = 0; j < 8; ++j) {
                int kidx = kbase + j;
                int c = kidx & 255, tap = kidx >> 8;
                pk.u[j] = (o < 18) ? f2bf(w_off[((size_t)o * C + c) * 9 + tap]) : (ushort_t)0;
            }
            *(short8*)(wOffA + (size_t)t2 * 8) = pk.v;
        }
    }
}

// ---------------------------------------------------------------------------
// K4: FUSED {offset-conv MFMA prologue + bilinear sample + bf16 MFMA GEMM}.
// The round-20-proven best (64.87 µs total): 256o x 32px per block, 512 thr,
// one barrier per tap (9 total), both subs staged per phase (32 LDS slots),
// A[8] batch-issued before blend+barrier (in flight across the non-draining
// barrier), 32 MFMAs per phase in two halves with A reloaded between halves,
// setprio around MFMA.  launch_bounds(512,2): ~105 live VGPR < 128 cap.
// Grid (bl,ho,pxh) = 256 blocks/launch.
// ---------------------------------------------------------------------------
__global__ __launch_bounds__(512, 2) void deform_pair(
    const ushort_t* __restrict__ xtB, const ushort_t* __restrict__ wOffA,
    const ushort_t* __restrict__ wPack, float* __restrict__ out, int pbase)
{
    __shared__ __align__(16) ushort_t sS[2][32][33][8];  // 33.8 KB (32 slots)
    __shared__ float sOff[18][32];                       // 2.3 KB
    __shared__ float sPart[8][18][32];                   // 18.4 KB (prologue)
    __shared__ int   sBase[2][128];                      // run bases (dbuf)
    __shared__ float sWgt[2][32][4];                     // per-px nbr weights

    int orig = blockIdx.x;
    int r = ((orig & 7) << 5) | (orig >> 3);   // XCD swizzle, 256 blocks
    int bl = r >> 7, ho = (r >> 1) & 63, pxh = r & 1;
    int tid = threadIdx.x;
    int lane = tid & 63, wv = tid >> 6;        // 8 waves
    int chunk = tid & 15, rq = (tid >> 4) & 31;  // staging: pixel rq, chunk

    const ushort_t* xtb = xtB + (size_t)bl * HW * C;
    int b = pbase + bl;

    // ---------------- offset-conv prologue (split-K MFMA) ----------------
    {
        const short8* wA = (const short8*)wOffA;
        f32x4 pacc[2][2];
        #pragma unroll
        for (int i = 0; i < 2; ++i)
            #pragma unroll
            for (int j = 0; j < 2; ++j) pacc[i][j] = (f32x4){0.f, 0.f, 0.f, 0.f};

        #pragma unroll 1
        for (int i = 0; i < 9; ++i) {
            int ks = wv * 9 + i;               // this wave's K-step
            int tap = ks >> 3, cs = ks & 7;
            int ky = tap / 3, kx = tap - ky * 3;
            int y  = ho - 1 + ky;
            int yc = min(max(y, 0), 63);
            bool yok = ((unsigned)y < 64u);
            short8 a0 = wA[(size_t)ks * 128 + lane];
            short8 a1 = wA[(size_t)ks * 128 + 64 + lane];
            #pragma unroll
            for (int pt = 0; pt < 2; ++pt) {
                int px = pxh * 32 + pt * 16 + (lane & 15);
                int xx = px - 1 + kx;
                bool ok = yok && ((unsigned)xx < 64u);
                unsigned msk = ok ? 0xffffffffu : 0u;
                int xc = min(max(xx, 0), 63);
                const ushort_t* srcb = xtb + (size_t)(yc * 64 + xc) * C
                                       + cs * 32 + (lane >> 4) * 8;
                union { u32x4 u; short8 s; } bv;
                bv.u = *(const u32x4*)srcb;
                bv.u[0] &= msk; bv.u[1] &= msk; bv.u[2] &= msk; bv.u[3] &= msk;
                pacc[0][pt] = __builtin_amdgcn_mfma_f32_16x16x32_bf16(a0, bv.s, pacc[0][pt], 0, 0, 0);
                pacc[1][pt] = __builtin_amdgcn_mfma_f32_16x16x32_bf16(a1, bv.s, pacc[1][pt], 0, 0, 0);
            }
        }
        // write partials (D: row=(l>>4)*4+j, col=l&15), only oc<18
        #pragma unroll
        for (int gt = 0; gt < 2; ++gt) {
            #pragma unroll
            for (int pt = 0; pt < 2; ++pt) {
                #pragma unroll
                for (int j = 0; j < 4; ++j) {
                    int oc = gt * 16 + (lane >> 4) * 4 + j;
                    if (oc < 18)
                        sPart[wv][oc][pt * 16 + (lane & 15)] = pacc[gt][pt][j];
                }
            }
        }
    }
    __syncthreads();
    for (int idx = tid; idx < 18 * 32; idx += 512) {
        int oc = idx >> 5, q = idx & 31;
        float s = 0.f;
        #pragma unroll
        for (int g = 0; g < 8; ++g) s += sPart[g][oc][q];
        sOff[oc][q] = s;
    }
    __syncthreads();

    // ---------------- main loop ----------------
    f32x4 acc2[2][2];
    #pragma unroll
    for (int i = 0; i < 2; ++i)
        #pragma unroll
        for (int j = 0; j < 2; ++j) acc2[i][j] = (f32x4){0.f, 0.f, 0.f, 0.f};

    // run bases + per-pixel neighbor weights (validity folded in), dbuf by tap
    auto computeBase = [&](int tap, int buf) {
        if (tid < 128) {
            int n = tid >> 5, q = tid & 31;
            int ky = tap / 3, kx = tap - ky * 3;
            float offy = sOff[2 * tap][q];
            float offx = sOff[2 * tap + 1][q];
            float py  = offy + (float)(ho - 1 + ky);
            float pxf = offx + (float)(pxh * 32 + q - 1 + kx);
            float y0f = floorf(py), x0f = floorf(pxf);
            float wy1 = py - y0f, wx1 = pxf - x0f;
            int y0 = (int)y0f, x0 = (int)x0f;
            int dy = n >> 1, dx = n & 1;
            int yy = y0 + dy, xx = x0 + dx;
            float wn = (dy ? wy1 : (1.f - wy1)) * (dx ? wx1 : (1.f - wx1));
            wn *= (((unsigned)yy < 64u) ? 1.f : 0.f) * (((unsigned)xx < 64u) ? 1.f : 0.f);
            int yc = min(max(yy, 0), 63), xc = min(max(xx, 0), 63);
            sBase[buf][tid] = (yc * 64 + xc) * C;
            sWgt[buf][q][n] = wn;
        }
    };

    auto loadBases = [&](int buf, int* rb) {
        #pragma unroll
        for (int n = 0; n < 4; ++n) rb[n] = sBase[buf][n * 32 + rq];
    };

    // coalesced: 8 x 16B, neighbor n of pixel rq, both subs
    auto issueBoth = [&](const int* rb, u32x4* La, u32x4* Lb) {
        #pragma unroll
        for (int n = 0; n < 4; ++n) {
            const ushort_t* p0 = xtb + rb[n] + chunk * 8;
            La[n] = *(const u32x4*)p0;
            Lb[n] = *(const u32x4*)(p0 + 128);
        }
    };

    // in-register blend: one pixel (rq), 4 neighbors -> one sS slot
    auto blendOne = [&](const u32x4* L, const float* w, int p, int slot) {
        unsigned pk[4];
        #pragma unroll
        for (int j = 0; j < 4; ++j) {
            float f0l = __uint_as_float(L[0][j] << 16);
            float f0h = __uint_as_float(L[0][j] & 0xffff0000u);
            float f1l = __uint_as_float(L[1][j] << 16);
            float f1h = __uint_as_float(L[1][j] & 0xffff0000u);
            float f2l = __uint_as_float(L[2][j] << 16);
            float f2h = __uint_as_float(L[2][j] & 0xffff0000u);
            float f3l = __uint_as_float(L[3][j] << 16);
            float f3h = __uint_as_float(L[3][j] & 0xffff0000u);
            float lo = fmaf(w[0], f0l, fmaf(w[1], f1l, fmaf(w[2], f2l, w[3] * f3l)));
            float hi = fmaf(w[0], f0h, fmaf(w[1], f1h, fmaf(w[2], f2h, w[3] * f3h)));
            asm("v_cvt_pk_bf16_f32 %0, %1, %2" : "=v"(pk[j]) : "v"(lo), "v"(hi));
        }
        u32x4 wvec = (u32x4){pk[0], pk[1], pk[2], pk[3]};
        *(u32x4*)&sS[p][slot][rq][0] = wvec;
    };

    int gt0 = wv * 2;
    const short8* wpB = (const short8*)wPack;

    // batch-issue the 8 A-fragments of one sub
    auto loadA8 = [&](int ks4base, short8* A) {
        #pragma unroll
        for (int h = 0; h < 4; ++h) {
            size_t an = ((size_t)(ks4base + h) * 16 + gt0) * 64 + lane;
            A[2 * h]     = wpB[an];
            A[2 * h + 1] = wpB[an + 64];
        }
    };

    auto mfmaHalf = [&](const short8* A, int p, int half) {
        __builtin_amdgcn_s_setprio(1);            // T5: favor MFMA wave
        #pragma unroll
        for (int h = 0; h < 4; ++h) {
            #pragma unroll
            for (int pt = 0; pt < 2; ++pt) {
                short8 bF = *(const short8*)&sS[p][half * 16 + h * 4 + (lane >> 4)][pt * 16 + (lane & 15)][0];
                acc2[0][pt] = __builtin_amdgcn_mfma_f32_16x16x32_bf16(A[2 * h],     bF, acc2[0][pt], 0, 0, 0);
                acc2[1][pt] = __builtin_amdgcn_mfma_f32_16x16x32_bf16(A[2 * h + 1], bF, acc2[1][pt], 0, 0, 0);
            }
        }
        __builtin_amdgcn_s_setprio(0);
    };

    u32x4 LA[4], LB[4];
    short8 A[8];

    // prologue of main pipeline
    computeBase(0, 0);
    block_sync_lds();
    {
        int rb0[4];
        loadBases(0, rb0);
        issueBoth(rb0, LA, LB);
    }

    int p = 0;
    #pragma unroll 1
    for (int tap = 0; tap < 9; ++tap) {
        float wcur[4];
        *(float4*)&wcur[0] = *(const float4*)&sWgt[tap & 1][rq][0];
        if (tap < 8) computeBase(tap + 1, (tap + 1) & 1);

        loadA8(tap * 8, A);                 // half-0 A: hides under blend+barrier
        blendOne(LA, wcur, p, chunk);       // sub0 -> slots 0..15
        blendOne(LB, wcur, p, 16 + chunk);  // sub1 -> slots 16..31
        block_sync_lds();                   // ONE barrier per tap

        int rb[4];
        if (tap < 8) { loadBases((tap + 1) & 1, rb); issueBoth(rb, LA, LB); }

        mfmaHalf(A, p, 0);                  // sub0: 16 MFMA
        loadA8(tap * 8 + 4, A);             // half-1 A: covered by MFMA pipe
        mfmaHalf(A, p, 1);                  // sub1: 16 MFMA
        p ^= 1;
    }

    // epilogue: D[row=(l>>4)*4+j][col=l&15]
    #pragma unroll
    for (int ot = 0; ot < 2; ++ot) {
        int o = wv * 32 + ot * 16 + (lane >> 4) * 4;
        #pragma unroll
        for (int pt = 0; pt < 2; ++pt) {
            int pxx = pxh * 32 + pt * 16 + (lane & 15);
            #pragma unroll
            for (int j = 0; j < 4; ++j)
                out[(((size_t)b * OCH + (o + j)) * H + ho) * W + pxx] = acc2[ot][pt][j];
        }
    }
}

// ---------------------------------------------------------------------------
extern "C" void kernel_launch(void* const* d_in, const int* in_sizes, int n_in,
                              void* d_out, int out_size, void* d_ws, size_t ws_size,
                              hipStream_t stream)
{
    const float* x     = (const float*)d_in[0];
    const float* w_off = (const float*)d_in[1];
    const float* w_def = (const float*)d_in[2];
    float* out = (float*)d_out;

    // ws: xt01[4.19MB] | wPack[1.18MB] | wOffA[147KB] = 5.52 MB (< proven 6.7).
    // xt23 lives in d_out's batch-0 region: written by prep, read by
    // deform(pbase=2) (writes out[b2,b3] only), then overwritten by
    // deform(pbase=0)'s out[b0] stores.
    ushort_t* xt01  = (ushort_t*)d_ws;
    ushort_t* wPack = xt01 + (size_t)2 * HW * C;
    ushort_t* wOffA = wPack + (size_t)NHS * 16 * 64 * 8;
    ushort_t* xtD   = (ushort_t*)d_out;   // batch 2,3 xt scratch

    prep_all<<<1348, 256, 0, stream>>>(x, w_def, w_off, xt01, xtD, wPack, wOffA);
    deform_pair<<<256, 512, 0, stream>>>(xtD, wOffA, wPack, out, 2);
    deform_pair<<<256, 512, 0, stream>>>(xt01, wOffA, wPack, out, 0);
}